// Round 1
// baseline (841.978 us; speedup 1.0000x reference)
//
#include <hip/hip_runtime.h>
#include <hip/hip_bf16.h>

// ---------------- constants (also derived from sizes at launch) -------------
#define HID 64

// ---------------- CSR build ------------------------------------------------
__global__ void hist_kernel(const int* __restrict__ dst, int* __restrict__ deg, int E) {
    int i = blockIdx.x * blockDim.x + threadIdx.x;
    if (i < E) atomicAdd(&deg[dst[i]], 1);
}

// exclusive scan within 256-blocks; blockSums gets the block total
__global__ void scan_block(const int* __restrict__ deg, int* __restrict__ rowp,
                           int* __restrict__ blockSums, int n) {
    __shared__ int tmp[256];
    int gid = blockIdx.x * 256 + threadIdx.x;
    int v = (gid < n) ? deg[gid] : 0;
    tmp[threadIdx.x] = v;
    __syncthreads();
    for (int off = 1; off < 256; off <<= 1) {
        int t = (threadIdx.x >= off) ? tmp[threadIdx.x - off] : 0;
        __syncthreads();
        tmp[threadIdx.x] += t;
        __syncthreads();
    }
    if (gid < n) rowp[gid] = tmp[threadIdx.x] - v;   // exclusive
    if (threadIdx.x == 255) blockSums[blockIdx.x] = tmp[255];
}

// single block, exclusive scan of up to 512 block sums (in place)
__global__ void scan_sums(int* __restrict__ blockSums, int nb) {
    __shared__ int tmp[512];
    int tid = threadIdx.x;
    int v = (tid < nb) ? blockSums[tid] : 0;
    tmp[tid] = v;
    __syncthreads();
    for (int off = 1; off < 512; off <<= 1) {
        int t = (tid >= off) ? tmp[tid - off] : 0;
        __syncthreads();
        tmp[tid] += t;
        __syncthreads();
    }
    if (tid < nb) blockSums[tid] = tmp[tid] - v;     // exclusive
}

__global__ void scan_add(int* __restrict__ rowp, const int* __restrict__ blockOff,
                         int* __restrict__ cursor, int n, int total) {
    int gid = blockIdx.x * blockDim.x + threadIdx.x;
    if (gid < n) {
        int v = rowp[gid] + blockOff[gid >> 8];
        rowp[gid] = v;
        cursor[gid] = v;
    }
    if (gid == n) rowp[n] = total;
}

__global__ void fill_kernel(const int* __restrict__ src, const int* __restrict__ dst,
                            int* __restrict__ cursor, int* __restrict__ col, int E) {
    int i = blockIdx.x * blockDim.x + threadIdx.x;
    if (i < E) {
        int d = dst[i];
        int p = atomicAdd(&cursor[d], 1);
        col[p] = src[i];
    }
}

// batch is sorted; bstart[g] = first node of graph g, bstart[G] = N
__global__ void batch_starts(const int* __restrict__ batch, int* __restrict__ bstart,
                             int n, int ngraph) {
    int i = blockIdx.x * blockDim.x + threadIdx.x;
    if (i >= n) return;
    int b = batch[i];
    int prev = (i == 0) ? -1 : batch[i - 1];
    for (int g = prev + 1; g <= b; ++g) bstart[g] = i;
    if (i == n - 1) {
        for (int g = b + 1; g <= ngraph; ++g) bstart[g] = n;
    }
}

// ---------------- per-layer kernels ----------------------------------------
// wave per node, lane = channel. agg[n][lane] = sum over in-edges of x[src][lane]
__global__ __launch_bounds__(256) void gather_kernel(
        const int* __restrict__ rowp, const int* __restrict__ col,
        const float* __restrict__ xsrc, float* __restrict__ agg, int n) {
    int wid = (blockIdx.x * 256 + threadIdx.x) >> 6;
    int lane = threadIdx.x & 63;
    if (wid >= n) return;
    int e0 = rowp[wid], e1 = rowp[wid + 1];
    float acc = 0.f;
    int e = e0;
    for (; e + 4 <= e1; e += 4) {
        int s0 = col[e], s1 = col[e + 1], s2 = col[e + 2], s3 = col[e + 3];
        float v0 = xsrc[(size_t)s0 * HID + lane];
        float v1 = xsrc[(size_t)s1 * HID + lane];
        float v2 = xsrc[(size_t)s2 * HID + lane];
        float v3 = xsrc[(size_t)s3 * HID + lane];
        acc += v0 + v1 + v2 + v3;
    }
    for (; e < e1; ++e) acc += xsrc[(size_t)col[e] * HID + lane];
    agg[(size_t)wid * HID + lane] = acc;
}

// thread per node: y = relu(agg@Wrel + brel + x@Wroot). Weight reads are
// wave-uniform -> scalar loads + SGPR-operand FMAs.
__global__ __launch_bounds__(256) void gemm_relu(
        const float* __restrict__ agg, const float* __restrict__ xin,
        float* __restrict__ xout, const float* __restrict__ Wrel,
        const float* __restrict__ brel, const float* __restrict__ Wroot, int n) {
    int node = blockIdx.x * 256 + threadIdx.x;
    if (node >= n) return;
    float acc[HID];
#pragma unroll
    for (int c = 0; c < HID; ++c) acc[c] = brel[c];
    const float4* a4 = reinterpret_cast<const float4*>(agg + (size_t)node * HID);
    const float4* x4 = reinterpret_cast<const float4*>(xin + (size_t)node * HID);
    for (int kq = 0; kq < HID / 4; ++kq) {
        float4 a  = a4[kq];
        float4 xv = x4[kq];
        const float* wr = Wrel  + kq * 4 * HID;
        const float* wo = Wroot + kq * 4 * HID;
#pragma unroll
        for (int c = 0; c < HID; ++c) {
            acc[c] += a.x  * wr[c]           + a.y  * wr[HID + c]
                    + a.z  * wr[2 * HID + c] + a.w  * wr[3 * HID + c]
                    + xv.x * wo[c]           + xv.y * wo[HID + c]
                    + xv.z * wo[2 * HID + c] + xv.w * wo[3 * HID + c];
        }
    }
    float4* o4 = reinterpret_cast<float4*>(xout + (size_t)node * HID);
#pragma unroll
    for (int cq = 0; cq < HID / 4; ++cq) {
        float4 v;
        v.x = fmaxf(acc[cq * 4 + 0], 0.f);
        v.y = fmaxf(acc[cq * 4 + 1], 0.f);
        v.z = fmaxf(acc[cq * 4 + 2], 0.f);
        v.w = fmaxf(acc[cq * 4 + 3], 0.f);
        o4[cq] = v;
    }
}

// block per graph (256 thr = 4 waves), sums y rows, accumulates into x_add
__global__ __launch_bounds__(256) void pool_kernel(
        const float* __restrict__ y, const int* __restrict__ bstart,
        float* __restrict__ x_add, int ngraph) {
    int g = blockIdx.x;
    if (g >= ngraph) return;
    int lane = threadIdx.x & 63;
    int w = threadIdx.x >> 6;
    __shared__ float part[4][HID];
    int s0 = bstart[g], s1 = bstart[g + 1];
    float acc = 0.f;
    for (int nd = s0 + w; nd < s1; nd += 4) acc += y[(size_t)nd * HID + lane];
    part[w][lane] = acc;
    __syncthreads();
    if (w == 0) {
        float t = part[0][lane] + part[1][lane] + part[2][lane] + part[3][lane];
        x_add[(size_t)g * HID + lane] += t;
    }
}

// block (64 threads) per graph: 64->64->32->1 MLP
__global__ __launch_bounds__(64) void mlp_kernel(
        const float* __restrict__ x_add,
        const float* __restrict__ W1, const float* __restrict__ b1,
        const float* __restrict__ W2, const float* __restrict__ b2,
        const float* __restrict__ W3, const float* __restrict__ b3,
        float* __restrict__ out, int ngraph) {
    int g = blockIdx.x;
    if (g >= ngraph) return;
    int lane = threadIdx.x;
    __shared__ float h1s[64];
    __shared__ float h2s[32];
    const float* xa = x_add + (size_t)g * HID;
    float s = b1[lane];
#pragma unroll
    for (int k = 0; k < 64; ++k) s += xa[k] * W1[k * 64 + lane];
    h1s[lane] = fmaxf(s, 0.f);
    __syncthreads();
    if (lane < 32) {
        float s2 = b2[lane];
#pragma unroll
        for (int k = 0; k < 64; ++k) s2 += h1s[k] * W2[k * 32 + lane];
        h2s[lane] = fmaxf(s2, 0.f);
    }
    __syncthreads();
    if (lane == 0) {
        float o = b3[0];
        for (int k = 0; k < 32; ++k) o += h2s[k] * W3[k];
        out[g] = o;
    }
}

// ---------------- launcher --------------------------------------------------
extern "C" void kernel_launch(void* const* d_in, const int* in_sizes, int n_in,
                              void* d_out, int out_size, void* d_ws, size_t ws_size,
                              hipStream_t stream) {
    const float* x0   = (const float*)d_in[0];
    const int*   ei   = (const int*)d_in[1];
    const int*   batch= (const int*)d_in[2];
    const float* Wrel = (const float*)d_in[3];
    const float* brel = (const float*)d_in[4];
    const float* Wroot= (const float*)d_in[5];
    const float* W1   = (const float*)d_in[6];
    const float* b1   = (const float*)d_in[7];
    const float* W2   = (const float*)d_in[8];
    const float* b2   = (const float*)d_in[9];
    const float* W3   = (const float*)d_in[10];
    const float* b3   = (const float*)d_in[11];
    float* out = (float*)d_out;

    const int N = in_sizes[0] / HID;       // 100000
    const int E = in_sizes[1] / 2;         // 1600000
    const int G = out_size;                // 1000 (OUT_C == 1)
    const int L = in_sizes[3] / (HID * HID); // 3

    const int* src = ei;
    const int* dst = ei + E;

    // ---- workspace carve-up (aligned to 256B) ----
    char* w = (char*)d_ws;
    size_t off = 0;
    auto alloc = [&](size_t bytes) {
        void* p = w + off;
        off += (bytes + 255) & ~(size_t)255;
        return p;
    };
    float* xA     = (float*)alloc((size_t)N * HID * 4);
    float* xB     = (float*)alloc((size_t)N * HID * 4);
    float* agg    = (float*)alloc((size_t)N * HID * 4);
    float* x_add  = (float*)alloc((size_t)G * HID * 4);
    int*   deg    = (int*)alloc((size_t)N * 4);
    int*   rowp   = (int*)alloc((size_t)(N + 1) * 4);
    int*   cursor = (int*)alloc((size_t)N * 4);
    int*   bsums  = (int*)alloc(1024 * 4);
    int*   col    = (int*)alloc((size_t)E * 4);
    int*   bstart = (int*)alloc((size_t)(G + 1) * 4);
    (void)ws_size;

    const int TB = 256;
    int nbScan = (N + TB - 1) / TB;

    // ---- CSR build ----
    hipMemsetAsync(deg, 0, (size_t)N * 4, stream);
    hipMemsetAsync(x_add, 0, (size_t)G * HID * 4, stream);
    hist_kernel<<<(E + TB - 1) / TB, TB, 0, stream>>>(dst, deg, E);
    scan_block<<<nbScan, TB, 0, stream>>>(deg, rowp, bsums, N);
    scan_sums<<<1, 512, 0, stream>>>(bsums, nbScan);
    scan_add<<<(N + 1 + TB - 1) / TB, TB, 0, stream>>>(rowp, bsums, cursor, N, E);
    fill_kernel<<<(E + TB - 1) / TB, TB, 0, stream>>>(src, dst, cursor, col, E);
    batch_starts<<<(N + TB - 1) / TB, TB, 0, stream>>>(batch, bstart, N, G);

    // ---- layers ----
    int gatherBlocks = (N * 64 + TB - 1) / TB;  // wave per node
    int gemmBlocks   = (N + TB - 1) / TB;
    for (int i = 0; i < L; ++i) {
        const float* xin  = (i == 0) ? x0 : ((i == 1) ? xA : xB);
        float*       xout = (i == 1) ? xB : xA;   // L0->xA, L1->xB, L2->xA
        gather_kernel<<<gatherBlocks, TB, 0, stream>>>(rowp, col, xin, agg, N);
        gemm_relu<<<gemmBlocks, TB, 0, stream>>>(agg, xin, xout,
                                                 Wrel + (size_t)i * HID * HID,
                                                 brel + (size_t)i * HID,
                                                 Wroot + (size_t)i * HID * HID, N);
        pool_kernel<<<G, TB, 0, stream>>>(xout, bstart, x_add, G);
    }

    // ---- final MLP ----
    mlp_kernel<<<G, 64, 0, stream>>>(x_add, W1, b1, W2, b2, W3, b3, out, G);
}

// Round 2
// 546.289 us; speedup vs baseline: 1.5413x; 1.5413x over previous
//
#include <hip/hip_runtime.h>
#include <hip/hip_bf16.h>

#define HID 64

typedef short  bf16x8 __attribute__((ext_vector_type(8)));
typedef float  f32x4  __attribute__((ext_vector_type(4)));

__device__ inline float bf2f(unsigned short u) {
    union { unsigned int i; float f; } v; v.i = ((unsigned int)u) << 16; return v.f;
}
__device__ inline unsigned short f2bf(float f) {
    union { float f; unsigned int i; } v; v.f = f;
    unsigned int u = v.i;
    u += 0x7FFFu + ((u >> 16) & 1u);      // round-to-nearest-even
    return (unsigned short)(u >> 16);
}

// ---------------- CSR build ------------------------------------------------
__global__ void hist_kernel(const int* __restrict__ dst, int* __restrict__ deg, int E) {
    int i = blockIdx.x * blockDim.x + threadIdx.x;
    if (i < E) atomicAdd(&deg[dst[i]], 1);
}

__global__ void scan_block(const int* __restrict__ deg, int* __restrict__ rowp,
                           int* __restrict__ blockSums, int n) {
    __shared__ int tmp[256];
    int gid = blockIdx.x * 256 + threadIdx.x;
    int v = (gid < n) ? deg[gid] : 0;
    tmp[threadIdx.x] = v;
    __syncthreads();
    for (int off = 1; off < 256; off <<= 1) {
        int t = (threadIdx.x >= off) ? tmp[threadIdx.x - off] : 0;
        __syncthreads();
        tmp[threadIdx.x] += t;
        __syncthreads();
    }
    if (gid < n) rowp[gid] = tmp[threadIdx.x] - v;
    if (threadIdx.x == 255) blockSums[blockIdx.x] = tmp[255];
}

__global__ void scan_sums(int* __restrict__ blockSums, int nb) {
    __shared__ int tmp[512];
    int tid = threadIdx.x;
    int v = (tid < nb) ? blockSums[tid] : 0;
    tmp[tid] = v;
    __syncthreads();
    for (int off = 1; off < 512; off <<= 1) {
        int t = (tid >= off) ? tmp[tid - off] : 0;
        __syncthreads();
        tmp[tid] += t;
        __syncthreads();
    }
    if (tid < nb) blockSums[tid] = tmp[tid] - v;
}

__global__ void scan_add(int* __restrict__ rowp, const int* __restrict__ blockOff,
                         int* __restrict__ cursor, int n, int total) {
    int gid = blockIdx.x * blockDim.x + threadIdx.x;
    if (gid < n) {
        int v = rowp[gid] + blockOff[gid >> 8];
        rowp[gid] = v;
        cursor[gid] = v;
    }
    if (gid == n) rowp[n] = total;
}

__global__ void fill_kernel(const int* __restrict__ src, const int* __restrict__ dst,
                            int* __restrict__ cursor, int* __restrict__ col, int E) {
    int i = blockIdx.x * blockDim.x + threadIdx.x;
    if (i < E) {
        int d = dst[i];
        int p = atomicAdd(&cursor[d], 1);
        col[p] = src[i];
    }
}

__global__ void batch_starts(const int* __restrict__ batch, int* __restrict__ bstart,
                             int n, int ngraph) {
    int i = blockIdx.x * blockDim.x + threadIdx.x;
    if (i >= n) return;
    int b = batch[i];
    int prev = (i == 0) ? -1 : batch[i - 1];
    for (int g = prev + 1; g <= b; ++g) bstart[g] = i;
    if (i == n - 1) {
        for (int g = b + 1; g <= ngraph; ++g) bstart[g] = n;
    }
}

// ---------------- dtype prep ------------------------------------------------
// x0 fp32 -> bf16 packed; i indexes float4s
__global__ void cvt_bf16(const float* __restrict__ x, unsigned int* __restrict__ xb, int n4) {
    int i = blockIdx.x * 256 + threadIdx.x;
    if (i >= n4) return;
    float4 v = reinterpret_cast<const float4*>(x)[i];
    xb[i * 2]     = ((unsigned int)f2bf(v.y) << 16) | f2bf(v.x);
    xb[i * 2 + 1] = ((unsigned int)f2bf(v.w) << 16) | f2bf(v.z);
}

// Wt[l][c][k] bf16, k<64 -> Wrel[l][k][c], k>=64 -> Wroot[l][k-64][c]
__global__ void prep_w(const float* __restrict__ Wrel, const float* __restrict__ Wroot,
                       unsigned short* __restrict__ Wt, int nl) {
    int i = blockIdx.x * 256 + threadIdx.x;
    if (i >= nl * 64 * 128) return;
    int k = i & 127, c = (i >> 7) & 63, l = i >> 13;
    float v = (k < 64) ? Wrel[(size_t)l * 4096 + k * 64 + c]
                       : Wroot[(size_t)l * 4096 + (k - 64) * 64 + c];
    Wt[i] = f2bf(v);
}

// ---------------- per-layer kernels ----------------------------------------
// wave per node; half-wave per edge; uint = 2 bf16 channels
__global__ __launch_bounds__(256) void gather_bf16(
        const int* __restrict__ rowp, const int* __restrict__ col,
        const unsigned int* __restrict__ xb,      // [N][32] uints
        unsigned int* __restrict__ aggb, int n) {
    int wid = (blockIdx.x * 256 + threadIdx.x) >> 6;
    int lane = threadIdx.x & 63;
    if (wid >= n) return;
    int h = lane >> 5, ch = lane & 31;
    int e0 = rowp[wid], e1 = rowp[wid + 1];
    float ax = 0.f, ay = 0.f;
    for (int e = e0 + h; e < e1; e += 2) {
        unsigned int p = xb[(size_t)col[e] * 32 + ch];
        ax += bf2f((unsigned short)(p & 0xFFFF));
        ay += bf2f((unsigned short)(p >> 16));
    }
    ax += __shfl(ax, lane ^ 32);
    ay += __shfl(ay, lane ^ 32);
    if (h == 0)
        aggb[(size_t)wid * 32 + ch] = ((unsigned int)f2bf(ay) << 16) | f2bf(ax);
}

// wave = 16 nodes x 64 cols; K=128 = [agg(64) || x(64)]; bf16 MFMA 16x16x32.
// A frag: lane l holds A[row=l&15][k = ks*32 + (l>>4)*8 + j] (contiguous k).
// B frag: lane l holds W[k][col=ct*16+(l&15)] read from Wt[col][k] (contiguous k).
// C/D: col = lane&15, row = 4*(lane>>4)+reg  (m89-verified).
__global__ __launch_bounds__(256) void gemm_mfma(
        const unsigned short* __restrict__ aggb, const unsigned short* __restrict__ xinb,
        unsigned short* __restrict__ yout,
        const unsigned short* __restrict__ Wt,   // [64][128]
        const float* __restrict__ brel, int n) {
    int wave = (blockIdx.x * 256 + threadIdx.x) >> 6;
    int lane = threadIdx.x & 63;
    int n0 = wave * 16;                 // N assumed multiple of 16 (100000 = 16*6250)
    if (n0 >= n) return;
    int r = lane & 15, kb = lane >> 4;
    f32x4 acc[4] = {};
    const unsigned short* arow = aggb + (size_t)(n0 + r) * 64 + kb * 8;
    const unsigned short* xrow = xinb + (size_t)(n0 + r) * 64 + kb * 8;
    const unsigned short* wrow = Wt + (size_t)r * 128 + kb * 8;
#pragma unroll
    for (int ks = 0; ks < 4; ++ks) {
        const unsigned short* ap = (ks < 2) ? (arow + (ks & 1) * 32)
                                            : (xrow + (ks & 1) * 32);
        bf16x8 a = *reinterpret_cast<const bf16x8*>(ap);
#pragma unroll
        for (int ct = 0; ct < 4; ++ct) {
            bf16x8 b = *reinterpret_cast<const bf16x8*>(wrow + (size_t)ct * 16 * 128 + ks * 32);
            acc[ct] = __builtin_amdgcn_mfma_f32_16x16x32_bf16(a, b, acc[ct], 0, 0, 0);
        }
    }
#pragma unroll
    for (int ct = 0; ct < 4; ++ct) {
        int c = ct * 16 + r;
        float bias = brel[c];
#pragma unroll
        for (int reg = 0; reg < 4; ++reg) {
            int node = n0 + kb * 4 + reg;
            float v = acc[ct][reg] + bias;
            yout[(size_t)node * 64 + c] = f2bf(fmaxf(v, 0.f));
        }
    }
}

// block per graph; 4 waves x 2 rows/iter; accumulate fp32 into x_add
__global__ __launch_bounds__(256) void pool_bf16(
        const unsigned int* __restrict__ y,      // [N][32]
        const int* __restrict__ bstart, float* __restrict__ x_add, int ngraph) {
    int g = blockIdx.x;
    if (g >= ngraph) return;
    int lane = threadIdx.x & 63, w = threadIdx.x >> 6;
    int h = lane >> 5, ch = lane & 31;
    __shared__ float2 part[4][32];
    int s0 = bstart[g], s1 = bstart[g + 1];
    float ax = 0.f, ay = 0.f;
    for (int nd = s0 + w * 2 + h; nd < s1; nd += 8) {
        unsigned int p = y[(size_t)nd * 32 + ch];
        ax += bf2f((unsigned short)(p & 0xFFFF));
        ay += bf2f((unsigned short)(p >> 16));
    }
    ax += __shfl(ax, lane ^ 32);
    ay += __shfl(ay, lane ^ 32);
    if (h == 0) part[w][ch] = make_float2(ax, ay);
    __syncthreads();
    if (threadIdx.x < 32) {
        float2 s = part[0][threadIdx.x];
        s.x += part[1][threadIdx.x].x + part[2][threadIdx.x].x + part[3][threadIdx.x].x;
        s.y += part[1][threadIdx.x].y + part[2][threadIdx.x].y + part[3][threadIdx.x].y;
        float2* xa = reinterpret_cast<float2*>(x_add + (size_t)g * 64);
        float2 cur = xa[threadIdx.x];
        xa[threadIdx.x] = make_float2(cur.x + s.x, cur.y + s.y);
    }
}

// block (64 threads) per graph: 64->64->32->1 MLP, fp32
__global__ __launch_bounds__(64) void mlp_kernel(
        const float* __restrict__ x_add,
        const float* __restrict__ W1, const float* __restrict__ b1,
        const float* __restrict__ W2, const float* __restrict__ b2,
        const float* __restrict__ W3, const float* __restrict__ b3,
        float* __restrict__ out, int ngraph) {
    int g = blockIdx.x;
    if (g >= ngraph) return;
    int lane = threadIdx.x;
    __shared__ float h1s[64];
    __shared__ float h2s[32];
    const float* xa = x_add + (size_t)g * HID;
    float s = b1[lane];
#pragma unroll
    for (int k = 0; k < 64; ++k) s += xa[k] * W1[k * 64 + lane];
    h1s[lane] = fmaxf(s, 0.f);
    __syncthreads();
    if (lane < 32) {
        float s2 = b2[lane];
#pragma unroll
        for (int k = 0; k < 64; ++k) s2 += h1s[k] * W2[k * 32 + lane];
        h2s[lane] = fmaxf(s2, 0.f);
    }
    __syncthreads();
    if (lane == 0) {
        float o = b3[0];
        for (int k = 0; k < 32; ++k) o += h2s[k] * W3[k];
        out[g] = o;
    }
}

// ---------------- launcher --------------------------------------------------
extern "C" void kernel_launch(void* const* d_in, const int* in_sizes, int n_in,
                              void* d_out, int out_size, void* d_ws, size_t ws_size,
                              hipStream_t stream) {
    const float* x0    = (const float*)d_in[0];
    const int*   ei    = (const int*)d_in[1];
    const int*   batch = (const int*)d_in[2];
    const float* Wrel  = (const float*)d_in[3];
    const float* brel  = (const float*)d_in[4];
    const float* Wroot = (const float*)d_in[5];
    const float* W1    = (const float*)d_in[6];
    const float* b1    = (const float*)d_in[7];
    const float* W2    = (const float*)d_in[8];
    const float* b2    = (const float*)d_in[9];
    const float* W3    = (const float*)d_in[10];
    const float* b3    = (const float*)d_in[11];
    float* out = (float*)d_out;

    const int N = in_sizes[0] / HID;          // 100000
    const int E = in_sizes[1] / 2;            // 1600000
    const int G = out_size;                   // 1000
    const int L = in_sizes[3] / (HID * HID);  // 3

    const int* src = ei;
    const int* dst = ei + E;

    char* w = (char*)d_ws;
    size_t off = 0;
    auto alloc = [&](size_t bytes) {
        void* p = w + off;
        off += (bytes + 255) & ~(size_t)255;
        return p;
    };
    unsigned short* xb0   = (unsigned short*)alloc((size_t)N * HID * 2);
    unsigned short* xbA   = (unsigned short*)alloc((size_t)N * HID * 2);
    unsigned short* xbB   = (unsigned short*)alloc((size_t)N * HID * 2);
    unsigned short* aggb  = (unsigned short*)alloc((size_t)N * HID * 2);
    unsigned short* Wt    = (unsigned short*)alloc((size_t)L * 64 * 128 * 2);
    float* x_add  = (float*)alloc((size_t)G * HID * 4);
    int*   deg    = (int*)alloc((size_t)N * 4);
    int*   rowp   = (int*)alloc((size_t)(N + 1) * 4);
    int*   cursor = (int*)alloc((size_t)N * 4);
    int*   bsums  = (int*)alloc(1024 * 4);
    int*   col    = (int*)alloc((size_t)E * 4);
    int*   bstart = (int*)alloc((size_t)(G + 1) * 4);
    (void)ws_size;

    const int TB = 256;
    int nbScan = (N + TB - 1) / TB;

    hipMemsetAsync(deg, 0, (size_t)N * 4, stream);
    hipMemsetAsync(x_add, 0, (size_t)G * HID * 4, stream);

    hist_kernel<<<(E + TB - 1) / TB, TB, 0, stream>>>(dst, deg, E);
    scan_block<<<nbScan, TB, 0, stream>>>(deg, rowp, bsums, N);
    scan_sums<<<1, 512, 0, stream>>>(bsums, nbScan);
    scan_add<<<(N + 1 + TB - 1) / TB, TB, 0, stream>>>(rowp, bsums, cursor, N, E);
    fill_kernel<<<(E + TB - 1) / TB, TB, 0, stream>>>(src, dst, cursor, col, E);
    batch_starts<<<(N + TB - 1) / TB, TB, 0, stream>>>(batch, bstart, N, G);

    cvt_bf16<<<(N * 16 + TB - 1) / TB, TB, 0, stream>>>(x0, (unsigned int*)xb0, N * 16);
    prep_w<<<(L * 64 * 128 + TB - 1) / TB, TB, 0, stream>>>(Wrel, Wroot, Wt, L);

    int gatherBlocks = (N * 64 + TB - 1) / TB;        // wave per node
    int gemmBlocks   = ((N + 15) / 16 * 64 + TB - 1) / TB;
    for (int i = 0; i < L; ++i) {
        const unsigned short* xin = (i == 0) ? xb0 : ((i == 1) ? xbA : xbB);
        unsigned short* xout = (i == 1) ? xbB : xbA;  // L0->xbA, L1->xbB, L2->xbA
        gather_bf16<<<gatherBlocks, TB, 0, stream>>>(rowp, col,
                (const unsigned int*)xin, (unsigned int*)aggb, N);
        gemm_mfma<<<gemmBlocks, TB, 0, stream>>>(aggb, xin, xout,
                Wt + (size_t)i * 64 * 128, brel + (size_t)i * HID, N);
        pool_bf16<<<G, TB, 0, stream>>>((const unsigned int*)xout, bstart, x_add, G);
    }

    mlp_kernel<<<G, 64, 0, stream>>>(x_add, W1, b1, W2, b2, W3, b3, out, G);
}